// Round 3
// baseline (665.875 us; speedup 1.0000x reference)
//
#include <hip/hip_runtime.h>
#include <hip/hip_cooperative_groups.h>
#include <stdint.h>

namespace cg = cooperative_groups;

typedef __attribute__((ext_vector_type(8))) short short8;
typedef __attribute__((ext_vector_type(4))) float floatx4;

__device__ inline unsigned short f2bf(float f) {
    unsigned int u = __float_as_uint(f);
    u += 0x7fffu + ((u >> 16) & 1u);   // round-to-nearest-even
    return (unsigned short)(u >> 16);
}

// ---------------------------------------------------------------------------
// Tile worker: average over E experts + transpose + fp32->bf16.
// src[e, k, n] row-major; dst[n, k] bf16, leading dim ldb.
// Rows n in [Nsrc, Ndst) zero-filled (pads rw2 N=100 -> 128).
// ---------------------------------------------------------------------------
__device__ void avg_transpose_tile(const float* __restrict__ src,
                                   unsigned short* __restrict__ dst,
                                   int E, int K, int Nsrc, int Ndst, int ldb,
                                   float scale, int tile_x, int tile_y) {
    __shared__ float tile[32][33];
    const int tid = threadIdx.x;
    const int tx = tid & 31;
    const int ty = tid >> 5;   // 0..7
    const int kb = tile_x * 32;
    const int nb = tile_y * 32;
#pragma unroll
    for (int p = 0; p < 4; ++p) {
        int kl = ty + p * 8;
        int k = kb + kl;
        int n = nb + tx;
        float s = 0.f;
        if (k < K && n < Nsrc) {
            for (int e = 0; e < E; ++e)
                s += src[(size_t)e * K * Nsrc + (size_t)k * Nsrc + n];
        }
        tile[kl][tx] = s * scale;
    }
    __syncthreads();
#pragma unroll
    for (int p = 0; p < 4; ++p) {
        int nl = ty + p * 8;
        int n = nb + nl;
        int k = kb + tx;
        if (n < Ndst && k < K)
            dst[(size_t)n * ldb + k] = f2bf(tile[tx][nl]);
    }
}

// ---------------------------------------------------------------------------
// Fused prep: weight transforms + bias means + stats zero + UNSCALED Xp pack
//   [0,1536)      pW0  avg+T  -> Wmt[:,0:1024]
//   [1536,2688)   pW1  avg+T  -> Wmt[:,1024:1792]
//   [2688,4224)   pWib avg+T  -> Wmt[:,1792:2816]
//   [4224,4736)   rw1  T      -> rw1t
//   [4736,4800)   rw2  T(pad) -> rw2t
//   [4800,4806)   bias means
//   [4806,4807)   zero stats (1280 floats)
//   [4807,10439)  pack [x0|x1|xib] -> Xp bf16 [8192,2816]
// ---------------------------------------------------------------------------
__global__ __launch_bounds__(256) void prep(
    const float* __restrict__ pW0, const float* __restrict__ pW1,
    const float* __restrict__ pWib, const float* __restrict__ rw1,
    const float* __restrict__ rw2, const float* __restrict__ pb0,
    const float* __restrict__ pb1, const float* __restrict__ pbib,
    const float* __restrict__ x0, const float* __restrict__ x1,
    const float* __restrict__ xib,
    unsigned short* __restrict__ Wmt, unsigned short* __restrict__ rw1t,
    unsigned short* __restrict__ rw2t, float* __restrict__ bm0,
    float* __restrict__ bm1, float* __restrict__ bm2,
    float* __restrict__ stats_zero, unsigned short* __restrict__ Xp) {
    int id = blockIdx.x;
    int tid = threadIdx.x;
    if (id < 1536) {
        avg_transpose_tile(pW0, Wmt + 0, 7, 1024, 1536, 1536, 2816, 1.f / 7.f,
                           id % 32, id / 32);
    } else if (id < 2688) {
        int t = id - 1536;
        avg_transpose_tile(pW1, Wmt + 1024, 7, 768, 1536, 1536, 2816, 1.f / 7.f,
                           t % 24, t / 24);
    } else if (id < 4224) {
        int t = id - 2688;
        avg_transpose_tile(pWib, Wmt + 1792, 7, 1024, 1536, 1536, 2816,
                           1.f / 7.f, t % 32, t / 32);
    } else if (id < 4736) {
        int t = id - 4224;
        avg_transpose_tile(rw1, rw1t, 1, 1024, 512, 512, 1024, 1.f, t % 32,
                           t / 32);
    } else if (id < 4800) {
        int t = id - 4736;
        avg_transpose_tile(rw2, rw2t, 1, 512, 100, 128, 512, 1.f, t % 16,
                           t / 16);
    } else if (id < 4806) {
        int i = (id - 4800) * 256 + tid;
        if (i < 1536) {
            float s0 = 0.f, s1 = 0.f, s2 = 0.f;
            for (int e = 0; e < 7; ++e) {
                s0 += pb0[e * 1536 + i];
                s1 += pb1[e * 1536 + i];
                s2 += pbib[e * 1536 + i];
            }
            const float inv = 1.f / 7.f;
            bm0[i] = s0 * inv; bm1[i] = s1 * inv; bm2[i] = s2 * inv;
        }
    } else if (id < 4807) {
        for (int i = tid; i < 1280; i += 256) stats_zero[i] = 0.f;
    } else {
        int base = (id - 4807) * 1024;  // vec4-group index; 5632 blocks x 4
#pragma unroll
        for (int k = 0; k < 4; ++k) {
            int i = base + k * 256 + tid;   // < 8192*704 exactly
            int b = i / 704;
            int g = i % 704;
            const float* src;
            int col;
            if (g < 256)      { src = x0 + (size_t)b * 1024 + g * 4;          col = g * 4; }
            else if (g < 448) { src = x1 + (size_t)b * 768 + (g - 256) * 4;   col = 1024 + (g - 256) * 4; }
            else              { src = xib + (size_t)b * 1024 + (g - 448) * 4; col = 1792 + (g - 448) * 4; }
            float4 v = *(const float4*)src;
            ushort4 o;
            o.x = f2bf(v.x); o.y = f2bf(v.y); o.z = f2bf(v.z); o.w = f2bf(v.w);
            *(ushort4*)(Xp + (size_t)b * 2816 + col) = o;
        }
    }
}

// ---------------------------------------------------------------------------
// Shared MFMA GEMM core: 128x128 tile, BK=32, 4 waves (2x2 of 64x64),
// global_load_lds width 16.  A row-major lda, Bt row-major ldb (B transposed).
// Accumulates into acc.  K % 32 == 0.
// ---------------------------------------------------------------------------
__device__ __forceinline__ void gemm_core(
    floatx4 (&acc)[4][4], const unsigned short* __restrict__ A, int lda,
    const unsigned short* __restrict__ Bt, int ldb, int K,
    unsigned short* As, unsigned short* Bs) {
    const int tid = threadIdx.x;
    const int lane = tid & 63;
    const int wv = tid >> 6;
    const int wm = (wv & 1) * 64;
    const int wn = (wv >> 1) * 64;
    const int quad = lane >> 4;
    const int lrow = lane & 15;
    const int srow = lane >> 2;
    const int scol = (lane & 3) * 8;
    for (int k0 = 0; k0 < K; k0 += 32) {
#pragma unroll
        for (int r = 0; r < 2; ++r) {
            int chunk = r * 4 + wv;
            const unsigned short* ga =
                A + (size_t)(chunk * 16 + srow) * lda + (k0 + scol);
            __builtin_amdgcn_global_load_lds(
                (const __attribute__((address_space(1))) void*)ga,
                (__attribute__((address_space(3))) void*)(As + chunk * 512),
                16, 0, 0);
            const unsigned short* gb =
                Bt + (size_t)(chunk * 16 + srow) * ldb + (k0 + scol);
            __builtin_amdgcn_global_load_lds(
                (const __attribute__((address_space(1))) void*)gb,
                (__attribute__((address_space(3))) void*)(Bs + chunk * 512),
                16, 0, 0);
        }
        __syncthreads();
        short8 af[4], bfr[4];
#pragma unroll
        for (int i = 0; i < 4; ++i)
            af[i] = *(const short8*)(As + (wm + i * 16 + lrow) * 32 + quad * 8);
#pragma unroll
        for (int j = 0; j < 4; ++j)
            bfr[j] = *(const short8*)(Bs + (wn + j * 16 + lrow) * 32 + quad * 8);
#pragma unroll
        for (int i = 0; i < 4; ++i)
#pragma unroll
            for (int j = 0; j < 4; ++j)
                acc[i][j] = __builtin_amdgcn_mfma_f32_16x16x32_bf16(
                    af[i], bfr[j], acc[i][j], 0, 0, 0);
        __syncthreads();
    }
}

// ---------------------------------------------------------------------------
// Cooperative router mega-kernel (grid = 256 blocks, all phases in one launch):
//  A: h1 = Xp[:,:1024] @ rw1t + rb1, BN1 stats -> sync -> BN1+relu -> h1n bf16
//  B: h2 = h1n @ rw2t + rb2 (64 blocks), BN2 stats -> sync
//  C: BN2+tanh+rw3+sigmoid+softmax (32 blocks) -> w0/w1/w2 + ratios
// ---------------------------------------------------------------------------
__global__ __launch_bounds__(256) void router_mega(
    const unsigned short* __restrict__ Xp,
    const unsigned short* __restrict__ rw1t,
    const unsigned short* __restrict__ rw2t, unsigned short* __restrict__ h1n,
    float* __restrict__ h2, const float* __restrict__ rb1,
    const float* __restrict__ rg1, const float* __restrict__ rbt1,
    const float* __restrict__ rb2, const float* __restrict__ rg2,
    const float* __restrict__ rbt2, const float* __restrict__ rw3,
    const float* __restrict__ rb3, float* __restrict__ sum1,
    float* __restrict__ sumsq1, float* __restrict__ sum2,
    float* __restrict__ sumsq2, float* __restrict__ r01,
    float* __restrict__ r12, float* __restrict__ w0p, float* __restrict__ w1p,
    float* __restrict__ w2p) {
    __shared__ __align__(16) unsigned short As[4096];
    __shared__ __align__(16) unsigned short Bs[4096];
    cg::grid_group grid = cg::this_grid();
    const int tid = threadIdx.x;
    const int lane = tid & 63;
    const int wv = tid >> 6;
    const int wm = (wv & 1) * 64;
    const int wn = (wv >> 1) * 64;
    const int quad = lane >> 4;
    const int lrow = lane & 15;
    const int bid = blockIdx.x;
    const float invB = 1.f / 8192.f;

    // ---- phase A ----
    {
        const int bm_off = (bid & 63) * 128;
        const int bn_off = (bid >> 6) * 128;
        floatx4 acc[4][4];
#pragma unroll
        for (int i = 0; i < 4; ++i)
#pragma unroll
            for (int j = 0; j < 4; ++j) acc[i][j] = (floatx4){0.f, 0.f, 0.f, 0.f};
        gemm_core(acc, Xp + (size_t)bm_off * 2816, 2816,
                  rw1t + (size_t)bn_off * 1024, 1024, 1024, As, Bs);
#pragma unroll
        for (int j = 0; j < 4; ++j) {
            int n = bn_off + wn + j * 16 + lrow;
            float bv = rb1[n];
            float s = 0.f, ss = 0.f;
#pragma unroll
            for (int i = 0; i < 4; ++i)
#pragma unroll
                for (int r = 0; r < 4; ++r) {
                    float v = acc[i][j][r] + bv;
                    s += v; ss += v * v;
                }
            s += __shfl_xor(s, 16); s += __shfl_xor(s, 32);
            ss += __shfl_xor(ss, 16); ss += __shfl_xor(ss, 32);
            if (quad == 0) { atomicAdd(&sum1[n], s); atomicAdd(&sumsq1[n], ss); }
        }
        __threadfence();
        grid.sync();
        __threadfence();
#pragma unroll
        for (int j = 0; j < 4; ++j) {
            int n = bn_off + wn + j * 16 + lrow;
            float bv = rb1[n];
            float mu = sum1[n] * invB;
            float var = sumsq1[n] * invB - mu * mu;
            float sc = rg1[n] * rsqrtf(var + 1e-5f);
            float sh = rbt1[n] - mu * sc;
#pragma unroll
            for (int i = 0; i < 4; ++i)
#pragma unroll
                for (int r = 0; r < 4; ++r) {
                    int mm = bm_off + wm + i * 16 + quad * 4 + r;
                    float v = acc[i][j][r] + bv;
                    float t = fmaxf(v * sc + sh, 0.f);
                    h1n[(size_t)mm * 512 + n] = f2bf(t);
                }
        }
    }
    __threadfence();
    grid.sync();
    __threadfence();

    // ---- phase B ----
    if (bid < 64) {
        const int bm_off = bid * 128;
        floatx4 acc[4][4];
#pragma unroll
        for (int i = 0; i < 4; ++i)
#pragma unroll
            for (int j = 0; j < 4; ++j) acc[i][j] = (floatx4){0.f, 0.f, 0.f, 0.f};
        gemm_core(acc, h1n + (size_t)bm_off * 512, 512, rw2t, 512, 512, As, Bs);
#pragma unroll
        for (int j = 0; j < 4; ++j) {
            int n = wn + j * 16 + lrow;
            bool nok = (n < 100);
            float bv = nok ? rb2[n] : 0.f;
            float s = 0.f, ss = 0.f;
#pragma unroll
            for (int i = 0; i < 4; ++i)
#pragma unroll
                for (int r = 0; r < 4; ++r) {
                    float v = acc[i][j][r] + bv;
                    int mm = bm_off + wm + i * 16 + quad * 4 + r;
                    if (nok) h2[(size_t)mm * 100 + n] = v;
                    s += v; ss += v * v;
                }
            s += __shfl_xor(s, 16); s += __shfl_xor(s, 32);
            ss += __shfl_xor(ss, 16); ss += __shfl_xor(ss, 32);
            if (quad == 0 && nok) { atomicAdd(&sum2[n], s); atomicAdd(&sumsq2[n], ss); }
        }
    }
    __threadfence();
    grid.sync();
    __threadfence();

    // ---- phase C ----
    if (bid < 32) {
        float* scf = (float*)As;          // 100 floats
        float* shf = scf + 128;           // 100 floats
        float* w3  = (float*)Bs;          // 300 floats
        float* b3  = w3 + 304;            // 3 floats
        if (tid < 100) {
            float mu = sum2[tid] * invB;
            float var = sumsq2[tid] * invB - mu * mu;
            float s = rg2[tid] * rsqrtf(var + 1e-5f);
            scf[tid] = s;
            shf[tid] = rbt2[tid] - mu * s;
        }
        for (int i = tid; i < 300; i += 256) w3[i] = rw3[i];
        if (tid < 3) b3[tid] = rb3[tid];
        __syncthreads();
        int row = bid * 256 + tid;
        const float* hr = h2 + (size_t)row * 100;
        float l0 = b3[0], l1 = b3[1], l2 = b3[2];
        for (int k = 0; k < 100; ++k) {
            float t = tanhf(hr[k] * scf[k] + shf[k]);
            l0 += t * w3[k * 3 + 0];
            l1 += t * w3[k * 3 + 1];
            l2 += t * w3[k * 3 + 2];
        }
        l0 = 1.f / (1.f + expf(-l0));
        l1 = 1.f / (1.f + expf(-l1));
        l2 = 1.f / (1.f + expf(-l2));
        float mx = fmaxf(l0, fmaxf(l1, l2));
        float e0 = expf(l0 - mx), e1 = expf(l1 - mx), e2 = expf(l2 - mx);
        float inv = 1.f / (e0 + e1 + e2);
        w0p[row] = e0 * inv;
        w1p[row] = e1 * inv;
        w2p[row] = e2 * inv;
        r01[row] = e0 / e1;   // w0/w1
        r12[row] = e1 / e2;   // w1/w2
    }
}

// ---------------------------------------------------------------------------
// Final GEMM: out = sum_s w_s * (x_s @ Wm_s) + sum_s w_s * bm_s, via
// per-segment accumulator rescaling (acc after seg2 = (w0/w2)G0+(w1/w2)G1+G2).
// ---------------------------------------------------------------------------
__global__ __launch_bounds__(256, 3) void gemm_final(
    const unsigned short* __restrict__ Xp, const unsigned short* __restrict__ Wmt,
    float* __restrict__ C, const float* __restrict__ r01,
    const float* __restrict__ r12, const float* __restrict__ w0p,
    const float* __restrict__ w1p, const float* __restrict__ w2p,
    const float* __restrict__ bm0, const float* __restrict__ bm1,
    const float* __restrict__ bm2) {
    __shared__ __align__(16) unsigned short As[4096];
    __shared__ __align__(16) unsigned short Bs[4096];
    const int tid = threadIdx.x;
    const int lane = tid & 63;
    const int wv = tid >> 6;
    const int wm = (wv & 1) * 64;
    const int wn = (wv >> 1) * 64;
    const int quad = lane >> 4;
    const int lrow = lane & 15;
    const int bm_off = blockIdx.x * 128;
    const int bn_off = blockIdx.y * 128;
    floatx4 acc[4][4];
#pragma unroll
    for (int i = 0; i < 4; ++i)
#pragma unroll
        for (int j = 0; j < 4; ++j) acc[i][j] = (floatx4){0.f, 0.f, 0.f, 0.f};

    const unsigned short* Ab = Xp + (size_t)bm_off * 2816;
    const unsigned short* Bb = Wmt + (size_t)bn_off * 2816;

    gemm_core(acc, Ab, 2816, Bb, 2816, 1024, As, Bs);
#pragma unroll
    for (int i = 0; i < 4; ++i)
#pragma unroll
        for (int r = 0; r < 4; ++r) {
            float f = r01[bm_off + wm + i * 16 + quad * 4 + r];
#pragma unroll
            for (int j = 0; j < 4; ++j) acc[i][j][r] *= f;
        }
    gemm_core(acc, Ab + 1024, 2816, Bb + 1024, 2816, 768, As, Bs);
#pragma unroll
    for (int i = 0; i < 4; ++i)
#pragma unroll
        for (int r = 0; r < 4; ++r) {
            float f = r12[bm_off + wm + i * 16 + quad * 4 + r];
#pragma unroll
            for (int j = 0; j < 4; ++j) acc[i][j][r] *= f;
        }
    gemm_core(acc, Ab + 1792, 2816, Bb + 1792, 2816, 1024, As, Bs);

#pragma unroll
    for (int i = 0; i < 4; ++i)
#pragma unroll
        for (int r = 0; r < 4; ++r) {
            int m = bm_off + wm + i * 16 + quad * 4 + r;
            float a0 = w0p[m], a1 = w1p[m], a2 = w2p[m];
#pragma unroll
            for (int j = 0; j < 4; ++j) {
                int n = bn_off + wn + j * 16 + lrow;
                C[(size_t)m * 1536 + n] =
                    a2 * acc[i][j][r] + a0 * bm0[n] + a1 * bm1[n] + a2 * bm2[n];
            }
        }
}

// per-row L2 normalization in place, one wave per row (1536 cols)
__global__ __launch_bounds__(256) void l2norm_rows(float* __restrict__ out) {
    int wv = threadIdx.x >> 6;
    int lane = threadIdx.x & 63;
    int row = blockIdx.x * 4 + wv;
    float4* rp = (float4*)(out + (size_t)row * 1536);
    float4 v[6];
    float ss = 0.f;
#pragma unroll
    for (int t = 0; t < 6; ++t) {
        v[t] = rp[lane + t * 64];
        ss += v[t].x * v[t].x + v[t].y * v[t].y + v[t].z * v[t].z + v[t].w * v[t].w;
    }
#pragma unroll
    for (int o = 32; o > 0; o >>= 1) ss += __shfl_xor(ss, o);
    float inv = 1.f / fmaxf(sqrtf(ss), 1e-12f);
#pragma unroll
    for (int t = 0; t < 6; ++t) {
        v[t].x *= inv; v[t].y *= inv; v[t].z *= inv; v[t].w *= inv;
        rp[lane + t * 64] = v[t];
    }
}

extern "C" void kernel_launch(void* const* d_in, const int* in_sizes, int n_in,
                              void* d_out, int out_size, void* d_ws,
                              size_t ws_size, hipStream_t stream) {
    (void)in_sizes; (void)n_in; (void)out_size; (void)ws_size;
    const float* x0   = (const float*)d_in[0];
    const float* x1   = (const float*)d_in[1];
    const float* xib  = (const float*)d_in[2];
    const float* pW0  = (const float*)d_in[3];
    const float* pb0  = (const float*)d_in[4];
    const float* pW1  = (const float*)d_in[5];
    const float* pb1  = (const float*)d_in[6];
    const float* pWib = (const float*)d_in[7];
    const float* pbib = (const float*)d_in[8];
    const float* rw1  = (const float*)d_in[9];
    const float* rb1  = (const float*)d_in[10];
    const float* rg1  = (const float*)d_in[11];
    const float* rbt1 = (const float*)d_in[12];
    const float* rw2  = (const float*)d_in[13];
    const float* rb2  = (const float*)d_in[14];
    const float* rg2  = (const float*)d_in[15];
    const float* rbt2 = (const float*)d_in[16];
    const float* rw3  = (const float*)d_in[17];
    const float* rb3  = (const float*)d_in[18];
    float* out = (float*)d_out;

    char* ws = (char*)d_ws;
    // --- workspace layout (~64.7 MB) ---
    unsigned short* Wmt = (unsigned short*)(ws);            // [1536,2816] bf16
    char* S = ws + 8650752;
    float* sum1   = (float*)(S + 0);        // 512
    float* sumsq1 = (float*)(S + 2048);     // 512
    float* sum2   = (float*)(S + 4096);     // 128
    float* sumsq2 = (float*)(S + 4608);     // 128   (zero region = 1280 f)
    float* bm0    = (float*)(S + 5120);     // 1536
    float* bm1    = (float*)(S + 11264);
    float* bm2    = (float*)(S + 17408);
    float* w0p    = (float*)(S + 23552);    // 8192
    float* w1p    = (float*)(S + 56320);
    float* w2p    = (float*)(S + 89088);
    float* r01    = (float*)(S + 121856);
    float* r12    = (float*)(S + 154624);   // ends S+187392
    unsigned short* rw1t = (unsigned short*)(ws + 8838144);  // [512,1024] bf16
    unsigned short* rw2t = (unsigned short*)(ws + 9886720);  // [128,512] bf16
    char* R = ws + 10017792;
    unsigned short* Xp  = (unsigned short*)(R);              // [8192,2816] bf16
    unsigned short* h1n = (unsigned short*)(R + 46137344);   // [8192,512] bf16
    float* h2           = (float*)(R + 54525952);            // [8192,100] f32

    // 1. prep: weight transforms + bias means + stats zero + Xp pack
    prep<<<10439, 256, 0, stream>>>(pW0, pW1, pWib, rw1, rw2, pb0, pb1, pbib,
                                    x0, x1, xib, Wmt, rw1t, rw2t, bm0, bm1,
                                    bm2, (float*)S, Xp);
    // 2. cooperative router mega-kernel
    {
        void* args[] = {(void*)&Xp,  (void*)&rw1t, (void*)&rw2t, (void*)&h1n,
                        (void*)&h2,  (void*)&rb1,  (void*)&rg1,  (void*)&rbt1,
                        (void*)&rb2, (void*)&rg2,  (void*)&rbt2, (void*)&rw3,
                        (void*)&rb3, (void*)&sum1, (void*)&sumsq1,
                        (void*)&sum2, (void*)&sumsq2, (void*)&r01, (void*)&r12,
                        (void*)&w0p, (void*)&w1p, (void*)&w2p};
        hipLaunchCooperativeKernel((void*)router_mega, dim3(256), dim3(256),
                                   args, 0, stream);
    }
    // 3. final GEMM with per-segment accumulator rescale
    gemm_final<<<dim3(64, 12), 256, 0, stream>>>(Xp, Wmt, out, r01, r12, w0p,
                                                 w1p, w2p, bm0, bm1, bm2);
    // 4. per-row L2 normalize
    l2norm_rows<<<2048, 256, 0, stream>>>(out);
}